// Round 21
// baseline (343.790 us; speedup 1.0000x reference)
//
#include <hip/hip_runtime.h>
#include <math.h>

#define NN    4096
#define KK    20
#define QQ    4                 // query points per lane (per wave)
#define WAVES 4
#define BLK   (WAVES*64)        // 256 threads
#define PPB   (WAVES*QQ)        // 16 points per block
#define PIT   16                // pair-iterations per phase (2 pairs/iter)
#define CAP   56                // per-point candidate capacity
#define BPB   (NN/PPB)          // 256 blocks per batch
#define BB    8

typedef float f32x4 __attribute__((ext_vector_type(4)));
typedef float f32x2 __attribute__((ext_vector_type(2)));

__device__ __forceinline__ unsigned fkey(float f) {  // monotone float->uint
  unsigned u = __float_as_uint(f);
  return u ^ ((unsigned)((int)u >> 31) | 0x80000000u);
}
__device__ __forceinline__ float fkey_inv(unsigned k) {
  unsigned u = (k & 0x80000000u) ? (k ^ 0x80000000u) : ~k;
  return __uint_as_float(u);
}

// one thread per point-PAIR: AoS table (feature) + pair-interleaved (scan)
__global__ void prep_kernel(const float* __restrict__ x,
                            float4* __restrict__ ws4,
                            f32x4* __restrict__ wspk) {
  const int p = blockIdx.x * 256 + threadIdx.x;        // 16384 pairs
  const float* s = x + (size_t)p * 6;
  const float x0 = s[0], y0 = s[1], z0 = s[2];
  const float x1 = s[3], y1 = s[4], z1 = s[5];
  const float w0 = fmaf(z0, z0, fmaf(y0, y0, x0 * x0));
  const float w1 = fmaf(z1, z1, fmaf(y1, y1, x1 * x1));
  ws4[2 * p]     = make_float4(x0, y0, z0, w0);
  ws4[2 * p + 1] = make_float4(x1, y1, z1, w1);
  wspk[2 * p]     = (f32x4){x0, x1, y0, y1};
  wspk[2 * p + 1] = (f32x4){z0, z1, w0, w1};
}

template<bool WS>
__global__ __launch_bounds__(BLK, 7)   // 72-VGPR budget: room for the pipeline
void edgeconv_kernel(const float* __restrict__ x,
                     const float4* __restrict__ ws4,
                     const f32x4* __restrict__ wspk,
                     const float* __restrict__ W,
                     const float* __restrict__ bias,
                     float* __restrict__ out) {
  __shared__ float2 cand[PPB][CAP + 1];                // 7.3 KB (d, j-bits)
  __shared__ int    jkeep[PPB][21];                    // 1.3 KB
  __shared__ int    pc[PPB];
  __shared__ int    pk[PPB];

  const int tid  = threadIdx.x;
  const int lane = tid & 63;
  const int w    = tid >> 6;
  // batch-per-CU swizzle (validated: FETCH 6.3 -> 4.1 MB in r18)
  const int bb   = blockIdx.x % BB;
  const int blk  = blockIdx.x / BB;
  const int base = bb * NN;
  const int g0   = w * QQ;                 // wave's first point group
  const int myp0 = blk * PPB + g0;

  // packed query coeffs: d' = |xj|^2 - 2*xi.xj (order-preserving per point;
  // self value is the strict global minimum and rides along)
  f32x2 nxp[QQ], nyp[QQ], nzp[QQ];
  #pragma unroll
  for (int q = 0; q < QQ; ++q) {
    const float* p = x + (size_t)(base + myp0 + q) * 3;
    const float a = -2.f * p[0], b = -2.f * p[1], c = -2.f * p[2];
    nxp[q] = (f32x2){a, a}; nyp[q] = (f32x2){b, b}; nzp[q] = (f32x2){c, c};
  }

  if (tid < PPB) { pc[tid] = 0; pk[tid] = 0; }
  __syncthreads();

  // pair loader: A=(x0,x1,y0,y1), Bv=(z0,z1,w0,w1); identical fma chain in
  // both paths -> bit-identical d'
  auto ldpair = [&](int pr, f32x4& A, f32x4& Bv) {
    if constexpr (WS) {
      A  = wspk[base + (pr << 1)];
      Bv = wspk[base + (pr << 1) + 1];
    } else {
      const float* s = x + ((size_t)base + ((size_t)pr << 1)) * 3;
      const float x0 = s[0], y0 = s[1], z0 = s[2];
      const float x1 = s[3], y1 = s[4], z1 = s[5];
      A  = (f32x4){x0, x1, y0, y1};
      Bv = (f32x4){z0, z1, fmaf(z0, z0, fmaf(y0, y0, x0 * x0)),
                           fmaf(z1, z1, fmaf(y1, y1, x1 * x1))};
    }
  };
  // AoS point loader (feature phase)
  auto ldp = [&](int j) -> float4 {
    if constexpr (WS) {
      return ws4[base + j];
    } else {
      const float* p = x + (size_t)(base + j) * 3;
      const float a = p[0], b = p[1], c = p[2];
      return make_float4(a, b, c, fmaf(c, c, fmaf(b, b, a * a)));
    }
  };
  // packed distance: v_pk_fma_f32 chain via builtin (scheduler-visible)
  auto pdist = [&](int q, const f32x4& A, const f32x4& Bv) -> f32x2 {
    return __builtin_elementwise_fma(nxp[q], A.xy,
            __builtin_elementwise_fma(nyp[q], A.zw,
             __builtin_elementwise_fma(nzp[q], Bv.xy, Bv.zw)));
  };

  // ---------------- Phase A: per-(lane,q) min; lane owns pairs pr=i*64+lane.
  //   Software-pipelined depth 2: next iteration's 4 loads are issued BEFORE
  //   computing the current batch, so memory and VALU stay overlapped even
  //   when the block's waves run in phase. ------------------------------------
  float m[QQ];
  #pragma unroll
  for (int q = 0; q < QQ; ++q) m[q] = INFINITY;
  {
    f32x4 A0, B0, A1, B1;
    ldpair(0 * 64 + lane, A0, B0);
    ldpair(1 * 64 + lane, A1, B1);
    #pragma unroll 2
    for (int i = 0; i < PIT; ++i) {
      f32x4 nA0, nB0, nA1, nB1;
      if (i + 1 < PIT) {
        ldpair((2 * (i + 1) + 0) * 64 + lane, nA0, nB0);
        ldpair((2 * (i + 1) + 1) * 64 + lane, nA1, nB1);
      }
      #pragma unroll
      for (int q = 0; q < QQ; ++q) {
        const f32x2 dA = pdist(q, A0, B0);
        const f32x2 dB = pdist(q, A1, B1);
        m[q] = fminf(fminf(m[q], fminf(dA.x, dA.y)), fminf(dB.x, dB.y));
      }
      A0 = nA0; B0 = nB0; A1 = nA1; B1 = nB1;
    }
  }

  // ---- tau_q = exact 21st smallest of the 64 lane-minima (>= true tau;
  //      exactly one self value in the set). Ballot radix bisection,
  //      sequential per q for register economy. ------------------------------
  float tau[QQ];
  #pragma unroll
  for (int q = 0; q < QQ; ++q) {
    const unsigned key = fkey(m[q]);
    unsigned lo = 0u, hi = 0xFFFFFFFFu;
    for (int b = 0; b < 32; ++b) {
      const unsigned mid = lo + ((hi - lo) >> 1);
      const unsigned long long bal = __ballot(key <= mid);
      if (__popcll(bal) > KK) hi = mid; else lo = mid + 1;
    }
    tau[q] = fkey_inv(lo);
  }

  // ---------------- Phase B: collect candidates d' <= tau_q (self included);
  //                  flat per-element checks; same depth-2 pipeline -----------
  {
    f32x4 A0, B0, A1, B1;
    ldpair(0 * 64 + lane, A0, B0);
    ldpair(1 * 64 + lane, A1, B1);
    #pragma unroll 2
    for (int i = 0; i < PIT; ++i) {
      f32x4 nA0, nB0, nA1, nB1;
      if (i + 1 < PIT) {
        ldpair((2 * (i + 1) + 0) * 64 + lane, nA0, nB0);
        ldpair((2 * (i + 1) + 1) * 64 + lane, nA1, nB1);
      }
      const int pr0 = (2 * i + 0) * 64 + lane;
      const int pr1 = (2 * i + 1) * 64 + lane;
      #pragma unroll
      for (int q = 0; q < QQ; ++q) {
        const f32x2 dA = pdist(q, A0, B0);
        const f32x2 dB = pdist(q, A1, B1);
        if (dA.x <= tau[q]) { const int wp = atomicAdd(&pc[g0 + q], 1);
          if (wp < CAP) cand[g0 + q][wp] = make_float2(dA.x, __int_as_float(2 * pr0)); }
        if (dA.y <= tau[q]) { const int wp = atomicAdd(&pc[g0 + q], 1);
          if (wp < CAP) cand[g0 + q][wp] = make_float2(dA.y, __int_as_float(2 * pr0 + 1)); }
        if (dB.x <= tau[q]) { const int wp = atomicAdd(&pc[g0 + q], 1);
          if (wp < CAP) cand[g0 + q][wp] = make_float2(dB.x, __int_as_float(2 * pr1)); }
        if (dB.y <= tau[q]) { const int wp = atomicAdd(&pc[g0 + q], 1);
          if (wp < CAP) cand[g0 + q][wp] = make_float2(dB.y, __int_as_float(2 * pr1 + 1)); }
      }
      A0 = nA0; B0 = nB0; A1 = nA1; B1 = nB1;
    }
  }
  __syncthreads();

  // ---- Rank + compact: keep j != self with lex-rank(d, j) <= 20 (exactly 20;
  //      matches top_k's low-index tie-break; kept SET deterministic) ---------
  {
    const int g   = tid >> 4;            // 16 helper threads per point
    const int k0  = tid & 15;
    const int myp = blk * PPB + g;
    const int n0  = pc[g];
    const int n   = n0 < CAP ? n0 : CAP;
    for (int k = k0; k < n; k += 16) {
      const float2 ck = cand[g][k];
      const float dk = ck.x; const int jk = __float_as_int(ck.y);
      int rank = 0;
      for (int k2 = 0; k2 < n; ++k2) {
        const float2 c2 = cand[g][k2];
        rank += (c2.x < dk || (c2.x == dk && __float_as_int(c2.y) < jk)) ? 1 : 0;
      }
      if (jk != myp && rank <= KK) jkeep[g][atomicAdd(&pk[g], 1)] = jk;
    }
  }
  __syncthreads();

  // ---------------- Feature phase: lane = channel; h = xj.w345 + const_i -----
  const float w3 = W[3*64+lane], w4 = W[4*64+lane], w5 = W[5*64+lane];
  const float c0 = W[0*64+lane] - w3;
  const float c1 = W[1*64+lane] - w4;
  const float c2 = W[2*64+lane] - w5;
  const float bo = bias[lane];

  for (int pi = 0; pi < QQ; ++pi) {          // wave's own 4 points
    const int p   = g0 + pi;
    const int pid = blk * PPB + p;
    const float4 xi = ldp(pid);              // query point (plain index)
    const float ci = fmaf(xi.x, c0, fmaf(xi.y, c1, fmaf(xi.z, c2, bo)));
    float hmax = -INFINITY;
    #pragma unroll 5
    for (int k = 0; k < KK; ++k) {           // exactly 20, wave-uniform
      const int j = __builtin_amdgcn_readfirstlane(jkeep[p][k]);  // scalar path
      const float4 xp = ldp(j);
      hmax = fmaxf(hmax, fmaf(xp.x, w3, fmaf(xp.y, w4, fmaf(xp.z, w5, ci))));
    }
    out[(size_t)(base + pid) * 64 + lane] = fmaxf(hmax, 0.0f);
  }
}

extern "C" void kernel_launch(void* const* d_in, const int* in_sizes, int n_in,
                              void* d_out, int out_size, void* d_ws, size_t ws_size,
                              hipStream_t stream) {
  const float* x  = (const float*)d_in[0];
  // d_in[1] = batch (implicit: i / N) — unused
  const float* W  = (const float*)d_in[2];
  const float* b  = (const float*)d_in[3];
  float* out = (float*)d_out;

  const size_t aosz = (size_t)BB * NN * sizeof(float4);   // 512 KB
  const size_t need = 2 * aosz;                           // 1 MB
  dim3 grid(BB * BPB);   // 2048 blocks
  dim3 block(BLK);
  if (ws_size >= need) {
    float4* ws4 = (float4*)d_ws;
    f32x4* wspk = (f32x4*)((char*)d_ws + aosz);
    hipLaunchKernelGGL(prep_kernel, dim3(BB * NN / 2 / 256), dim3(256), 0, stream,
                       x, ws4, wspk);
    hipLaunchKernelGGL((edgeconv_kernel<true>), grid, block, 0, stream,
                       x, ws4, wspk, W, b, out);
  } else {
    hipLaunchKernelGGL((edgeconv_kernel<false>), grid, block, 0, stream,
                       x, (const float4*)nullptr, (const f32x4*)nullptr, W, b, out);
  }
}

// Round 22
// 71.629 us; speedup vs baseline: 4.7996x; 4.7996x over previous
//
#include <hip/hip_runtime.h>
#include <math.h>

#define NN    4096
#define KK    20
#define QQ    4                 // query points per lane (per wave)
#define WAVES 4
#define BLK   (WAVES*64)        // 256 threads
#define PPB   (WAVES*QQ)        // 16 points per block
#define PIT   16                // pair-iterations per phase (2 pairs/iter)
#define CAP   56                // per-point candidate capacity
#define BPB   (NN/PPB)          // 256 blocks per batch
#define BB    8

typedef float f32x4 __attribute__((ext_vector_type(4)));
typedef float f32x2 __attribute__((ext_vector_type(2)));

__device__ __forceinline__ unsigned fkey(float f) {  // monotone float->uint
  unsigned u = __float_as_uint(f);
  return u ^ ((unsigned)((int)u >> 31) | 0x80000000u);
}
__device__ __forceinline__ float fkey_inv(unsigned k) {
  unsigned u = (k & 0x80000000u) ? (k ^ 0x80000000u) : ~k;
  return __uint_as_float(u);
}

// one thread per point-PAIR: AoS table (feature) + pair-interleaved (scan)
__global__ void prep_kernel(const float* __restrict__ x,
                            float4* __restrict__ ws4,
                            f32x4* __restrict__ wspk) {
  const int p = blockIdx.x * 256 + threadIdx.x;        // 16384 pairs
  const float* s = x + (size_t)p * 6;
  const float x0 = s[0], y0 = s[1], z0 = s[2];
  const float x1 = s[3], y1 = s[4], z1 = s[5];
  const float w0 = fmaf(z0, z0, fmaf(y0, y0, x0 * x0));
  const float w1 = fmaf(z1, z1, fmaf(y1, y1, x1 * x1));
  ws4[2 * p]     = make_float4(x0, y0, z0, w0);
  ws4[2 * p + 1] = make_float4(x1, y1, z1, w1);
  wspk[2 * p]     = (f32x4){x0, x1, y0, y1};
  wspk[2 * p + 1] = (f32x4){z0, z1, w0, w1};
}

template<bool WS>
__global__ __launch_bounds__(BLK, 8)
void edgeconv_kernel(const float* __restrict__ x,
                     const float4* __restrict__ ws4,
                     const f32x4* __restrict__ wspk,
                     const float* __restrict__ W,
                     const float* __restrict__ bias,
                     float* __restrict__ out) {
  __shared__ float2 cand[PPB][CAP + 1];                // 7.3 KB (d, j-bits)
  __shared__ int    jkeep[PPB][21];                    // 1.3 KB
  __shared__ int    pc[PPB];
  __shared__ int    pk[PPB];

  const int tid  = threadIdx.x;
  const int lane = tid & 63;
  const int w    = tid >> 6;
  // batch-per-CU swizzle: co-resident blocks share one batch table
  // (validated r18: FETCH 6.3 -> 4.1 MB)
  const int bb   = blockIdx.x % BB;
  const int blk  = blockIdx.x / BB;
  const int base = bb * NN;
  const int g0   = w * QQ;                 // wave's first point group
  const int myp0 = blk * PPB + g0;

  // packed query coeffs: d' = |xj|^2 - 2*xi.xj (order-preserving per point;
  // self value is the strict global minimum and rides along)
  f32x2 nxp[QQ], nyp[QQ], nzp[QQ];
  #pragma unroll
  for (int q = 0; q < QQ; ++q) {
    const float* p = x + (size_t)(base + myp0 + q) * 3;
    const float a = -2.f * p[0], b = -2.f * p[1], c = -2.f * p[2];
    nxp[q] = (f32x2){a, a}; nyp[q] = (f32x2){b, b}; nzp[q] = (f32x2){c, c};
  }

  if (tid < PPB) { pc[tid] = 0; pk[tid] = 0; }
  __syncthreads();

  // pair loader: A=(x0,x1,y0,y1), Bv=(z0,z1,w0,w1); identical fma chain in
  // both paths -> bit-identical d'
  auto ldpair = [&](int pr, f32x4& A, f32x4& Bv) {
    if constexpr (WS) {
      A  = wspk[base + (pr << 1)];
      Bv = wspk[base + (pr << 1) + 1];
    } else {
      const float* s = x + ((size_t)base + ((size_t)pr << 1)) * 3;
      const float x0 = s[0], y0 = s[1], z0 = s[2];
      const float x1 = s[3], y1 = s[4], z1 = s[5];
      A  = (f32x4){x0, x1, y0, y1};
      Bv = (f32x4){z0, z1, fmaf(z0, z0, fmaf(y0, y0, x0 * x0)),
                           fmaf(z1, z1, fmaf(y1, y1, x1 * x1))};
    }
  };
  // AoS point loader (feature phase)
  auto ldp = [&](int j) -> float4 {
    if constexpr (WS) {
      return ws4[base + j];
    } else {
      const float* p = x + (size_t)(base + j) * 3;
      const float a = p[0], b = p[1], c = p[2];
      return make_float4(a, b, c, fmaf(c, c, fmaf(b, b, a * a)));
    }
  };
  // packed distance: v_pk_fma_f32 chain via builtin (scheduler-visible)
  auto pdist = [&](int q, const f32x4& A, const f32x4& Bv) -> f32x2 {
    return __builtin_elementwise_fma(nxp[q], A.xy,
            __builtin_elementwise_fma(nyp[q], A.zw,
             __builtin_elementwise_fma(nzp[q], Bv.xy, Bv.zw)));
  };

  // ---------------- Phase A: per-(lane,q) min; lane owns pairs pr=i*64+lane --
  float m[QQ];
  #pragma unroll
  for (int q = 0; q < QQ; ++q) m[q] = INFINITY;
  #pragma unroll 1
  for (int i = 0; i < PIT; ++i) {
    f32x4 A0, B0, A1, B1;
    ldpair((2 * i + 0) * 64 + lane, A0, B0);
    ldpair((2 * i + 1) * 64 + lane, A1, B1);
    #pragma unroll
    for (int q = 0; q < QQ; ++q) {
      const f32x2 dA = pdist(q, A0, B0);
      const f32x2 dB = pdist(q, A1, B1);
      m[q] = fminf(fminf(m[q], fminf(dA.x, dA.y)), fminf(dB.x, dB.y));
    }
  }

  // ---- tau_q: 16-bit-PREFIX ballot bisection (16 steps, half of 32-bit).
  //      lo = smallest prefix with count(prefix <= lo) >= 21; the prefix
  //      ceiling (lo<<16)|0xFFFF is >= the exact 21st-smallest lane-min
  //      >= true tau. Looseness is one ~0.8%-relative bucket (~0.3 extra
  //      candidates expected; CAP=56 absorbs). Rank phase stays exact. -------
  float tau[QQ];
  #pragma unroll
  for (int q = 0; q < QQ; ++q) {
    const unsigned kp = fkey(m[q]) >> 16;
    unsigned lo = 0u, hi = 0xFFFFu;
    for (int b = 0; b < 16; ++b) {
      const unsigned mid = lo + ((hi - lo) >> 1);
      const unsigned long long bal = __ballot(kp <= mid);
      if (__popcll(bal) > KK) hi = mid; else lo = mid + 1;
    }
    tau[q] = fkey_inv((lo << 16) | 0xFFFFu);
  }

  // ---------------- Phase B: collect candidates d' <= tau_q (self included);
  //                  flat per-element checks (gates lose to wave-union) -------
  #pragma unroll 1
  for (int i = 0; i < PIT; ++i) {
    const int pr0 = (2 * i + 0) * 64 + lane;
    const int pr1 = (2 * i + 1) * 64 + lane;
    f32x4 A0, B0, A1, B1;
    ldpair(pr0, A0, B0);
    ldpair(pr1, A1, B1);
    #pragma unroll
    for (int q = 0; q < QQ; ++q) {
      const f32x2 dA = pdist(q, A0, B0);
      const f32x2 dB = pdist(q, A1, B1);
      if (dA.x <= tau[q]) { const int wp = atomicAdd(&pc[g0 + q], 1);
        if (wp < CAP) cand[g0 + q][wp] = make_float2(dA.x, __int_as_float(2 * pr0)); }
      if (dA.y <= tau[q]) { const int wp = atomicAdd(&pc[g0 + q], 1);
        if (wp < CAP) cand[g0 + q][wp] = make_float2(dA.y, __int_as_float(2 * pr0 + 1)); }
      if (dB.x <= tau[q]) { const int wp = atomicAdd(&pc[g0 + q], 1);
        if (wp < CAP) cand[g0 + q][wp] = make_float2(dB.x, __int_as_float(2 * pr1)); }
      if (dB.y <= tau[q]) { const int wp = atomicAdd(&pc[g0 + q], 1);
        if (wp < CAP) cand[g0 + q][wp] = make_float2(dB.y, __int_as_float(2 * pr1 + 1)); }
    }
  }
  __syncthreads();

  // ---- Rank + compact: keep j != self with lex-rank(d, j) <= 20 (exactly 20;
  //      matches top_k's low-index tie-break; kept SET deterministic) ---------
  {
    const int g   = tid >> 4;            // 16 helper threads per point
    const int k0  = tid & 15;
    const int myp = blk * PPB + g;
    const int n0  = pc[g];
    const int n   = n0 < CAP ? n0 : CAP;
    for (int k = k0; k < n; k += 16) {
      const float2 ck = cand[g][k];
      const float dk = ck.x; const int jk = __float_as_int(ck.y);
      int rank = 0;
      for (int k2 = 0; k2 < n; ++k2) {
        const float2 c2 = cand[g][k2];
        rank += (c2.x < dk || (c2.x == dk && __float_as_int(c2.y) < jk)) ? 1 : 0;
      }
      if (jk != myp && rank <= KK) jkeep[g][atomicAdd(&pk[g], 1)] = jk;
    }
  }
  __syncthreads();

  // ---------------- Feature phase: lane = channel; h = xj.w345 + const_i -----
  const float w3 = W[3*64+lane], w4 = W[4*64+lane], w5 = W[5*64+lane];
  const float c0 = W[0*64+lane] - w3;
  const float c1 = W[1*64+lane] - w4;
  const float c2 = W[2*64+lane] - w5;
  const float bo = bias[lane];

  for (int pi = 0; pi < QQ; ++pi) {          // wave's own 4 points
    const int p   = g0 + pi;
    const int pid = blk * PPB + p;
    const float4 xi = ldp(pid);              // query point (plain index)
    const float ci = fmaf(xi.x, c0, fmaf(xi.y, c1, fmaf(xi.z, c2, bo)));
    float hmax = -INFINITY;
    #pragma unroll 5
    for (int k = 0; k < KK; ++k) {           // exactly 20, wave-uniform
      const int j = __builtin_amdgcn_readfirstlane(jkeep[p][k]);  // scalar path
      const float4 xp = ldp(j);
      hmax = fmaxf(hmax, fmaf(xp.x, w3, fmaf(xp.y, w4, fmaf(xp.z, w5, ci))));
    }
    out[(size_t)(base + pid) * 64 + lane] = fmaxf(hmax, 0.0f);
  }
}

extern "C" void kernel_launch(void* const* d_in, const int* in_sizes, int n_in,
                              void* d_out, int out_size, void* d_ws, size_t ws_size,
                              hipStream_t stream) {
  const float* x  = (const float*)d_in[0];
  // d_in[1] = batch (implicit: i / N) — unused
  const float* W  = (const float*)d_in[2];
  const float* b  = (const float*)d_in[3];
  float* out = (float*)d_out;

  const size_t aosz = (size_t)BB * NN * sizeof(float4);   // 512 KB
  const size_t need = 2 * aosz;                           // 1 MB
  dim3 grid(BB * BPB);   // 2048 blocks
  dim3 block(BLK);
  if (ws_size >= need) {
    float4* ws4 = (float4*)d_ws;
    f32x4* wspk = (f32x4*)((char*)d_ws + aosz);
    hipLaunchKernelGGL(prep_kernel, dim3(BB * NN / 2 / 256), dim3(256), 0, stream,
                       x, ws4, wspk);
    hipLaunchKernelGGL((edgeconv_kernel<true>), grid, block, 0, stream,
                       x, ws4, wspk, W, b, out);
  } else {
    hipLaunchKernelGGL((edgeconv_kernel<false>), grid, block, 0, stream,
                       x, (const float4*)nullptr, (const f32x4*)nullptr, W, b, out);
  }
}